// Round 4
// baseline (329.218 us; speedup 1.0000x reference)
//
#include <hip/hip_runtime.h>

// MRR on MI355X — R10: fused cooperative kernel, full occupancy + pipelined.
// N_TOT = 8192 + 8192*4000 = 32,776,192 elems; nvec = N_TOT/4 vint4.
//
// Evidence trail:
//  - ~226 us of dur_us is harness poison fills (3x 512MB @ ~7 TB/s),
//    irreducible. Two-kernel R6 = 286 us total (~60 us kernels).
//  - R7 failure re-attributed: absmax=1.0 == "rank 1 everywhere" == stale
//    poison pos (468) -> count 0. Plain relaxed agent stores aren't
//    cross-XCD visible; atomicExch RMW (R8/R9, absmax 0.0) is. Coop
//    launch at grid=512 was never the problem.
//  - R8: code[] in VGPRs spilled (WRITE_SIZE 20.8MB) -> 82 us.
//  - R9: no code[], but VGPR_Count=16 (reg-minimizer serialized loads,
//    ~1 outstanding load/thread) + coop GRID=256 = 1 blk/CU = 16 waves/CU
//    (Occupancy 41%) -> latency-bound 101 us @ 2.0 TB/s.
//  - R5 lesson: NO __threadfence (emits buffer_wbl2+buffer_inv, 3x slower).
//
// R10 changes vs R9:
//  - Coop GRID=512 x BLK=1024: 2 blk/CU (132KB LDS <= 160KB), 32 waves/CU
//    — same occupancy as the proven R6 count_kernel. Launch rc checked;
//    fallback to proven two-kernel path on any error.
//  - Phase B software-pipelined (prefetch next idx/pv before processing
//    current) so >= 2 loads stay in flight even at minimal VGPR.
//
// ws layout: [0,32K) pos floats; [32K, 32K+16392) u64 cnt[2048]+ticket;
// [56K) u32 grid-barrier cell (hipMemsetAsync'd to 0, poison-proof).

constexpr int N_POS = 8192;
constexpr int N_NEG = 4000;
constexpr int NSLOT = N_POS / 4;      // 2048 packed u64 count slots
constexpr int GRID  = 512;            // 2 blk/CU co-resident
constexpr int BLK   = 1024;
constexpr int CNT_BLOCKS = 512;       // fallback path

typedef int   vint4   __attribute__((ext_vector_type(4)));
typedef float vfloat4 __attribute__((ext_vector_type(4)));
typedef unsigned int u32;
typedef unsigned long long u64;

// ---------------------------------------------------------------- fused ----
__global__ __launch_bounds__(BLK, 8) void fused_mrr_kernel(
    const vint4* __restrict__ idx4, const float* __restrict__ pvs,
    float* __restrict__ pos, u64* __restrict__ cnt, u32* __restrict__ bar,
    float* __restrict__ out, int nvec) {
  __shared__ float pos_lds[N_POS];    // 32 KB
  __shared__ u32   lcnt[N_POS];       // 32 KB
  __shared__ float wsum[BLK / 64];
  __shared__ int   is_last;
  const int tid = threadIdx.x;
  const int gid = blockIdx.x * BLK + tid;
  const int stride = GRID * BLK;
  const vfloat4* __restrict__ pv4 = (const vfloat4*)pvs;

#pragma unroll
  for (int i = 0; i < N_POS / BLK; ++i) lcnt[tid + i * BLK] = 0u;
  // zero cnt slots + ticket via RMW (coherence point, vmcnt-tracked)
  if (gid <= NSLOT) (void)atomicExch(&cnt[gid], 0ull);

  // ---- Phase A: stream idx (PLAIN loads -> lands/stays in L3), scatter
  // pos via agent-RMW (cross-XCD visible). Proven R6 scatter body. ----
  {
    int j = gid;
#define SC_ELEM(V, JJ)                                                 \
  if ((V).x < N_POS) (void)atomicExch(&pos[(V).x], pvs[4 * (JJ) + 0]); \
  if ((V).y < N_POS) (void)atomicExch(&pos[(V).y], pvs[4 * (JJ) + 1]); \
  if ((V).z < N_POS) (void)atomicExch(&pos[(V).z], pvs[4 * (JJ) + 2]); \
  if ((V).w < N_POS) (void)atomicExch(&pos[(V).w], pvs[4 * (JJ) + 3]);
    for (; j + stride < nvec; j += 2 * stride) {
      vint4 a = idx4[j];
      vint4 b = idx4[j + stride];
      SC_ELEM(a, j)
      SC_ELEM(b, j + stride)
    }
    for (; j < nvec; j += stride) {
      vint4 a = idx4[j];
      SC_ELEM(a, j)
    }
#undef SC_ELEM
  }

  // ---- fence-free grid barrier (proven R8/R9) ----
  __builtin_amdgcn_s_waitcnt(0);   // all RMWs globally complete
  __syncthreads();
  if (tid == 0) {
    __hip_atomic_fetch_add(bar, 1u, __ATOMIC_RELAXED,
                           __HIP_MEMORY_SCOPE_AGENT);
    while (__hip_atomic_load(bar, __ATOMIC_RELAXED,
                             __HIP_MEMORY_SCOPE_AGENT) < (u32)GRID)
      __builtin_amdgcn_s_sleep(4);
  }
  __syncthreads();

  // ---- Phase B: stage pos (coherence-point atomic loads), re-stream idx
  // (L3 hits) + pv (NT, single use), count. Software-pipelined. ----
#pragma unroll
  for (int i = 0; i < N_POS / BLK; ++i) {
    const int s = tid + i * BLK;
    pos_lds[s] = __hip_atomic_load(&pos[s], __ATOMIC_RELAXED,
                                   __HIP_MEMORY_SCOPE_AGENT);
  }
  __syncthreads();

  {
#define CT_ELEM(IV, XV)                                              \
  if ((IV) >= N_POS) {                                               \
    unsigned r = (unsigned)((IV) - N_POS) / (unsigned)N_NEG;         \
    if ((XV) > pos_lds[r]) atomicAdd(&lcnt[r], 1u);                  \
  }
#define CT_VEC(V, X)                                                 \
  CT_ELEM((V).x, (X).x) CT_ELEM((V).y, (X).y)                        \
  CT_ELEM((V).z, (X).z) CT_ELEM((V).w, (X).w)
    int j = gid;
    if (j < nvec) {
      vint4 va = idx4[j];
      vfloat4 xa = __builtin_nontemporal_load(&pv4[j]);
      for (int jn = j + stride; jn < nvec; jn += stride) {
        vint4 vb = idx4[jn];                                  // prefetch
        vfloat4 xb = __builtin_nontemporal_load(&pv4[jn]);    // prefetch
        CT_VEC(va, xa)                                        // process cur
        va = vb;
        xa = xb;
      }
      CT_VEC(va, xa)                                          // epilogue
    }
#undef CT_VEC
#undef CT_ELEM
  }
  __syncthreads();

  // Flush LDS counters -> packed u64 device-scope atomics (16-bit fields,
  // per-row totals <= 4000, never carry).
  for (int s = tid; s < NSLOT; s += BLK) {
    u32 c0 = lcnt[4 * s + 0], c1 = lcnt[4 * s + 1];
    u32 c2 = lcnt[4 * s + 2], c3 = lcnt[4 * s + 3];
    u64 p = (u64)c0 | ((u64)c1 << 16) | ((u64)c2 << 32) | ((u64)c3 << 48);
    if (p) atomicAdd(&cnt[s], p);
  }

  // ---- last-block-done finalize (fence-free ticket, proven) ----
  __builtin_amdgcn_s_waitcnt(0);
  __syncthreads();
  if (tid == 0) {
    u64 prev = __hip_atomic_fetch_add(&cnt[NSLOT], 1ull, __ATOMIC_RELAXED,
                                      __HIP_MEMORY_SCOPE_AGENT);
    is_last = (prev == (u64)(GRID - 1));
  }
  __syncthreads();
  if (!is_last) return;

  float lsum = 0.f;
  for (int s = tid; s < NSLOT; s += BLK) {
    u64 p = __hip_atomic_load(&cnt[s], __ATOMIC_RELAXED,
                              __HIP_MEMORY_SCOPE_AGENT);
    float m0 = 1.0f / (float)(1u + (u32)(p & 0xFFFFu));
    float m1 = 1.0f / (float)(1u + (u32)((p >> 16) & 0xFFFFu));
    float m2 = 1.0f / (float)(1u + (u32)((p >> 32) & 0xFFFFu));
    float m3 = 1.0f / (float)(1u + (u32)((p >> 48) & 0xFFFFu));
    vfloat4 m = {m0, m1, m2, m3};
    *(vfloat4*)&out[1 + 4 * s] = m;
    lsum += m0 + m1 + m2 + m3;
  }
#pragma unroll
  for (int off = 32; off > 0; off >>= 1) lsum += __shfl_down(lsum, off, 64);
  if ((tid & 63) == 0) wsum[tid >> 6] = lsum;
  __syncthreads();
  if (tid == 0) {
    float tot = 0.f;
#pragma unroll
    for (int w = 0; w < BLK / 64; ++w) tot += wsum[w];
    out[0] = tot / (float)N_POS;
  }
}

// ------------------------------------------------- proven R6 fallback ----
__global__ __launch_bounds__(256) void scatter_pos_kernel(
    const vint4* __restrict__ idx4, const float* __restrict__ pv,
    float* __restrict__ pos, u64* __restrict__ cnt, int nvec) {
  const int gtid = blockIdx.x * 256 + threadIdx.x;
  if (gtid <= NSLOT) cnt[gtid] = 0ull;
  const int stride = gridDim.x * 256;
  int j = gtid;
#define SC_ELEM(V, JJ)                                   \
  if ((V).x < N_POS) pos[(V).x] = pv[4 * (JJ) + 0];      \
  if ((V).y < N_POS) pos[(V).y] = pv[4 * (JJ) + 1];      \
  if ((V).z < N_POS) pos[(V).z] = pv[4 * (JJ) + 2];      \
  if ((V).w < N_POS) pos[(V).w] = pv[4 * (JJ) + 3];
  for (; j + stride < nvec; j += 2 * stride) {
    vint4 a = idx4[j];
    vint4 b = idx4[j + stride];
    SC_ELEM(a, j)
    SC_ELEM(b, j + stride)
  }
  for (; j < nvec; j += stride) {
    vint4 a = idx4[j];
    SC_ELEM(a, j)
  }
#undef SC_ELEM
}

__global__ __launch_bounds__(1024) void count_kernel(
    const vint4* __restrict__ idx4, const vfloat4* __restrict__ pv4,
    const float* __restrict__ pos, u64* __restrict__ cnt,
    float* __restrict__ out, int nvec) {
  __shared__ float pos_lds[N_POS];
  __shared__ u32   lcnt[N_POS];
  __shared__ float wsum[16];
  __shared__ int is_last;
  for (int i = threadIdx.x; i < N_POS; i += 1024) {
    pos_lds[i] = pos[i];
    lcnt[i] = 0u;
  }
  __syncthreads();

  const int stride = gridDim.x * 1024;
  int j = blockIdx.x * 1024 + threadIdx.x;
#define CT_ELEM(IV, XV)                                              \
  if ((IV) >= N_POS) {                                               \
    unsigned r = (unsigned)((IV) - N_POS) / (unsigned)N_NEG;         \
    if ((XV) > pos_lds[r]) atomicAdd(&lcnt[r], 1u);                  \
  }
#define CT_VEC(V, X)                                                 \
  CT_ELEM((V).x, (X).x) CT_ELEM((V).y, (X).y)                        \
  CT_ELEM((V).z, (X).z) CT_ELEM((V).w, (X).w)
  for (; j + stride < nvec; j += 2 * stride) {
    vint4 va = idx4[j];
    vint4 vb = idx4[j + stride];
    vfloat4 xa = __builtin_nontemporal_load(&pv4[j]);
    vfloat4 xb = __builtin_nontemporal_load(&pv4[j + stride]);
    CT_VEC(va, xa)
    CT_VEC(vb, xb)
  }
  for (; j < nvec; j += stride) {
    vint4 va = idx4[j];
    vfloat4 xa = __builtin_nontemporal_load(&pv4[j]);
    CT_VEC(va, xa)
  }
#undef CT_VEC
#undef CT_ELEM
  __syncthreads();

  for (int s = threadIdx.x; s < NSLOT; s += 1024) {
    u32 c0 = lcnt[4 * s + 0], c1 = lcnt[4 * s + 1];
    u32 c2 = lcnt[4 * s + 2], c3 = lcnt[4 * s + 3];
    u64 p = (u64)c0 | ((u64)c1 << 16) | ((u64)c2 << 32) | ((u64)c3 << 48);
    if (p) atomicAdd(&cnt[s], p);
  }

  __builtin_amdgcn_s_waitcnt(0);
  __syncthreads();
  if (threadIdx.x == 0) {
    u64 prev = __hip_atomic_fetch_add(&cnt[NSLOT], 1ull, __ATOMIC_RELAXED,
                                      __HIP_MEMORY_SCOPE_AGENT);
    is_last = (prev == (u64)(gridDim.x - 1));
  }
  __syncthreads();
  if (!is_last) return;

  float lsum = 0.f;
  for (int s = threadIdx.x; s < NSLOT; s += 1024) {
    u64 p = __hip_atomic_load(&cnt[s], __ATOMIC_RELAXED,
                              __HIP_MEMORY_SCOPE_AGENT);
    float m0 = 1.0f / (float)(1u + (u32)(p & 0xFFFFu));
    float m1 = 1.0f / (float)(1u + (u32)((p >> 16) & 0xFFFFu));
    float m2 = 1.0f / (float)(1u + (u32)((p >> 32) & 0xFFFFu));
    float m3 = 1.0f / (float)(1u + (u32)((p >> 48) & 0xFFFFu));
    vfloat4 m = {m0, m1, m2, m3};
    *(vfloat4*)&out[1 + 4 * s] = m;
    lsum += m0 + m1 + m2 + m3;
  }
#pragma unroll
  for (int off = 32; off > 0; off >>= 1) lsum += __shfl_down(lsum, off, 64);
  if ((threadIdx.x & 63) == 0) wsum[threadIdx.x >> 6] = lsum;
  __syncthreads();
  if (threadIdx.x == 0) {
    float tot = 0.f;
#pragma unroll
    for (int w = 0; w < 16; ++w) tot += wsum[w];
    out[0] = tot / (float)N_POS;
  }
}

extern "C" void kernel_launch(void* const* d_in, const int* in_sizes, int n_in,
                              void* d_out, int out_size, void* d_ws,
                              size_t ws_size, hipStream_t stream) {
  const float* pv = (const float*)d_in[0];
  const vint4* idx4 = (const vint4*)d_in[1];
  float* out = (float*)d_out;
  float* pos = (float*)d_ws;
  u64* cnt = (u64*)((char*)d_ws + 32 * 1024);   // 2048 slots + ticket
  u32* bar = (u32*)((char*)d_ws + 56 * 1024);   // grid-barrier cell
  int nvec = in_sizes[0] / 4;                   // 8,194,048

  // Poison fill trashed ws: zero the barrier cell (stream-ordered, tiny).
  hipMemsetAsync(bar, 0, sizeof(u32), stream);

  void* args[] = {(void*)&idx4, (void*)&pv, (void*)&pos, (void*)&cnt,
                  (void*)&bar,  (void*)&out, (void*)&nvec};
  hipError_t e = hipLaunchCooperativeKernel((const void*)fused_mrr_kernel,
                                            dim3(GRID), dim3(BLK), args, 0,
                                            stream);
  if (e != hipSuccess) {
    // Proven two-kernel path (R6, 286 us).
    scatter_pos_kernel<<<2048, 256, 0, stream>>>(idx4, pv, pos, cnt, nvec);
    count_kernel<<<CNT_BLOCKS, 1024, 0, stream>>>(idx4, (const vfloat4*)pv,
                                                  pos, cnt, out, nvec);
  }
}

// Round 5
// 287.260 us; speedup vs baseline: 1.1461x; 1.1461x over previous
//
#include <hip/hip_runtime.h>

// MRR on MI355X — R11: REVERT to proven R6 two-kernel structure + x4 ILP.
// N_TOT = 8192 + 8192*4000 = 32,776,192 (divisible by 4).
// argsort(index) of a permutation is its inverse: element j is pos slot
// index[j] if index[j] < 8192, else neg of row (index[j]-8192)/4000.
//
// Evidence trail (why this structure):
//  - ~226 us of every dur_us is harness restore/poison fills (3x ~75 us
//    512 MB fillBuffer @ ~87% HBM peak) — irreducible. Kernel budget ~60 us.
//  - R6 two-kernel = 286.2 us total. PROVEN BEST.
//  - R7-R10 fused-cooperative experiments: 313/317/329 us. Post-mortems:
//    R8 spilled code[] (WRITE 20.8MB scratch); R9 1 blk/CU latency-bound;
//    R10 L3-warm replays STILL 114 us @ VALUBusy 7.9% => the coop
//    spin-barrier single-grid structure is issue-bound, not fixable by
//    occupancy/pipelining. ABANDONED — do not retry fusion.
//  - R8 proved idx stays L3-resident across iterations (FETCH ~= pv only),
//    so count_kernel's idx re-read is cheap; register row-codes pointless.
//  - R5 lesson: NO __threadfence (buffer_wbl2+buffer_inv, 3x slower).
//    Cross-kernel pos/cnt handoff via kernel-boundary coherence (proven).
//
// R11 delta vs R6: count_kernel main loop x2 -> x4 strided unroll
// (8 loads in flight/thread, ~48 VGPR, still 2 blk/CU @ 64KB LDS).
//
// ws layout: [0,32KB) pos floats; [32KB..) u64 cnt[2048] (4x16-bit rows per
// u64; per-row totals <= 4000 so fields never carry) + u64 ticket at [2048].

constexpr int N_POS = 8192;
constexpr int N_NEG = 4000;
constexpr int NSLOT = N_POS / 4;
constexpr int CNT_BLOCKS = 512;

typedef int   vint4   __attribute__((ext_vector_type(4)));
typedef float vfloat4 __attribute__((ext_vector_type(4)));
typedef unsigned int u32;
typedef unsigned long long u64;

// Pass 1: zero cnt+ticket + scatter the 8192 pos values. idx read #1
// (131 MB, plain loads so lines land in L3 for pass 2's re-read).
__global__ __launch_bounds__(256) void scatter_pos_kernel(
    const vint4* __restrict__ idx4, const float* __restrict__ pv,
    float* __restrict__ pos, u64* __restrict__ cnt, int nvec) {
  const int gtid = blockIdx.x * 256 + threadIdx.x;
  if (gtid <= NSLOT) cnt[gtid] = 0ull;   // slots 0..2047 + ticket at 2048
  const int stride = gridDim.x * 256;
  int j = gtid;
#define SC_ELEM(V, JJ)                                   \
  if ((V).x < N_POS) pos[(V).x] = pv[4 * (JJ) + 0];      \
  if ((V).y < N_POS) pos[(V).y] = pv[4 * (JJ) + 1];      \
  if ((V).z < N_POS) pos[(V).z] = pv[4 * (JJ) + 2];      \
  if ((V).w < N_POS) pos[(V).w] = pv[4 * (JJ) + 3];
  for (; j + stride < nvec; j += 2 * stride) {
    vint4 a = idx4[j];
    vint4 b = idx4[j + stride];
    SC_ELEM(a, j)
    SC_ELEM(b, j + stride)
  }
  for (; j < nvec; j += stride) {
    vint4 a = idx4[j];
    SC_ELEM(a, j)
  }
#undef SC_ELEM
}

// Pass 2: stream idx (#2, L3-resident) + pv (NT, single use). LDS pos stage
// + unpacked u32 LDS counters; flush as packed u64 device-scope atomics;
// last block (relaxed ticket, post-barrier so all atomics drained) computes
// sample_mrr + mean. NO agent fences anywhere.
__global__ __launch_bounds__(1024) void count_kernel(
    const vint4* __restrict__ idx4, const vfloat4* __restrict__ pv4,
    const float* __restrict__ pos, u64* __restrict__ cnt,
    float* __restrict__ out, int nvec) {
  __shared__ float pos_lds[N_POS];   // 32 KB
  __shared__ u32   lcnt[N_POS];      // 32 KB -> 64 KB total: 2 blk/CU,
                                     // 1024 thr = 32 waves/CU (full occ)
  __shared__ float wsum[16];
  __shared__ int is_last;
  for (int i = threadIdx.x; i < N_POS; i += 1024) {
    pos_lds[i] = pos[i];
    lcnt[i] = 0u;
  }
  __syncthreads();

  const int stride = gridDim.x * 1024;
  int j = blockIdx.x * 1024 + threadIdx.x;
#define CT_ELEM(IV, XV)                                              \
  if ((IV) >= N_POS) {                                               \
    unsigned r = (unsigned)((IV) - N_POS) / (unsigned)N_NEG;         \
    if ((XV) > pos_lds[r]) atomicAdd(&lcnt[r], 1u);                  \
  }
#define CT_VEC(V, X)                                                 \
  CT_ELEM((V).x, (X).x) CT_ELEM((V).y, (X).y)                        \
  CT_ELEM((V).z, (X).z) CT_ELEM((V).w, (X).w)
  // x4 strided unroll: 8 independent loads in flight per thread.
  for (; j + 3 * stride < nvec; j += 4 * stride) {
    vint4 va = idx4[j];
    vint4 vb = idx4[j + stride];
    vint4 vc = idx4[j + 2 * stride];
    vint4 vd = idx4[j + 3 * stride];
    vfloat4 xa = __builtin_nontemporal_load(&pv4[j]);
    vfloat4 xb = __builtin_nontemporal_load(&pv4[j + stride]);
    vfloat4 xc = __builtin_nontemporal_load(&pv4[j + 2 * stride]);
    vfloat4 xd = __builtin_nontemporal_load(&pv4[j + 3 * stride]);
    CT_VEC(va, xa)
    CT_VEC(vb, xb)
    CT_VEC(vc, xc)
    CT_VEC(vd, xd)
  }
  for (; j < nvec; j += stride) {
    vint4 va = idx4[j];
    vfloat4 xa = __builtin_nontemporal_load(&pv4[j]);
    CT_VEC(va, xa)
  }
#undef CT_VEC
#undef CT_ELEM
  __syncthreads();

  // Flush LDS counters -> packed u64 device-scope atomics (bypass L1/L2,
  // land at the coherence point; vmcnt tracks completion).
  for (int s = threadIdx.x; s < NSLOT; s += 1024) {
    u32 c0 = lcnt[4 * s + 0], c1 = lcnt[4 * s + 1];
    u32 c2 = lcnt[4 * s + 2], c3 = lcnt[4 * s + 3];
    u64 p = (u64)c0 | ((u64)c1 << 16) | ((u64)c2 << 32) | ((u64)c3 << 48);
    if (p) atomicAdd(&cnt[s], p);
  }

  // ---- last-block-done finalize, fence-free ----
  // __syncthreads drains vmcnt(0) per wave (compiler-guaranteed barrier
  // semantics), so every atomic from this block is globally complete here.
  __builtin_amdgcn_s_waitcnt(0);   // belt-and-braces: vmcnt/lgkmcnt = 0
  __syncthreads();
  if (threadIdx.x == 0) {
    u64 prev = __hip_atomic_fetch_add(&cnt[NSLOT], 1ull, __ATOMIC_RELAXED,
                                      __HIP_MEMORY_SCOPE_AGENT);
    is_last = (prev == (u64)(gridDim.x - 1));
  }
  __syncthreads();
  if (!is_last) return;

  float lsum = 0.f;
  for (int s = threadIdx.x; s < NSLOT; s += 1024) {
    u64 p = __hip_atomic_load(&cnt[s], __ATOMIC_RELAXED,
                              __HIP_MEMORY_SCOPE_AGENT);  // cache-bypassing
    float m0 = 1.0f / (float)(1u + (u32)(p & 0xFFFFu));
    float m1 = 1.0f / (float)(1u + (u32)((p >> 16) & 0xFFFFu));
    float m2 = 1.0f / (float)(1u + (u32)((p >> 32) & 0xFFFFu));
    float m3 = 1.0f / (float)(1u + (u32)((p >> 48) & 0xFFFFu));
    vfloat4 m = {m0, m1, m2, m3};
    *(vfloat4*)&out[1 + 4 * s] = m;
    lsum += m0 + m1 + m2 + m3;
  }
#pragma unroll
  for (int off = 32; off > 0; off >>= 1) lsum += __shfl_down(lsum, off, 64);
  if ((threadIdx.x & 63) == 0) wsum[threadIdx.x >> 6] = lsum;
  __syncthreads();
  if (threadIdx.x == 0) {
    float tot = 0.f;
#pragma unroll
    for (int w = 0; w < 16; ++w) tot += wsum[w];
    out[0] = tot / (float)N_POS;
  }
}

extern "C" void kernel_launch(void* const* d_in, const int* in_sizes, int n_in,
                              void* d_out, int out_size, void* d_ws, size_t ws_size,
                              hipStream_t stream) {
  const float* pv = (const float*)d_in[0];
  const int* idx = (const int*)d_in[1];
  float* out = (float*)d_out;
  float* pos = (float*)d_ws;
  u64* cnt = (u64*)((char*)d_ws + 32 * 1024);   // 2048 slots + ticket
  int nvec = in_sizes[0] / 4;   // 8,194,048

  scatter_pos_kernel<<<2048, 256, 0, stream>>>((const vint4*)idx, pv, pos,
                                               cnt, nvec);
  count_kernel<<<CNT_BLOCKS, 1024, 0, stream>>>((const vint4*)idx,
                                                (const vfloat4*)pv, pos, cnt,
                                                out, nvec);
}